// Round 14
// baseline (303.121 us; speedup 1.0000x reference)
//
#include <hip/hip_runtime.h>
#include <cstddef>
#include <cstdint>

// Problem: B=2, S=2048, E=1024, H=16, D=64.  Softmax over HEADS (ref quirk).
#define BATCH 2
#define S_LEN 2048
#define E_DIM 1024
#define NH    16
#define HD    64
#define M_ROWS (BATCH * S_LEN)   // 4096

// fold softmax scale into Q at projection time: 1/sqrt(64) * log2(e)
#define QSCALE 0.18033688011112042f

typedef unsigned short u16;
typedef short     bf16x8 __attribute__((ext_vector_type(8)));
typedef _Float16  f16x8  __attribute__((ext_vector_type(8)));
typedef __fp16    h16x2  __attribute__((ext_vector_type(2)));   // cvt_pkrtz return type
typedef float     f32x4  __attribute__((ext_vector_type(4)));

__device__ __forceinline__ u16 f2bf(float f) {
    union { float f; unsigned u; } v; v.f = f;
    unsigned r = v.u + 0x7fffu + ((v.u >> 16) & 1u);   // RNE
    return (u16)(r >> 16);
}
__device__ __forceinline__ float bf2f(u16 h) {
    union { unsigned u; float f; } v; v.u = ((unsigned)h) << 16;
    return v.f;
}

// async global->LDS DMA, 16 B per lane (global_load_lds_dwordx4).
__device__ __forceinline__ void load_lds16(const u16* g, u16* l) {
    __builtin_amdgcn_global_load_lds(
        (const __attribute__((address_space(1))) unsigned int*)g,
        (__attribute__((address_space(3))) unsigned int*)l, 16, 0, 0);
}

// ---------------------------------------------------------------------------
// fp32 -> bf16 bulk convert (n % 4 == 0)
// ---------------------------------------------------------------------------
__global__ void cvt_bf16(const float* __restrict__ in, u16* __restrict__ out, int n)
{
    int i = (blockIdx.x * 256 + threadIdx.x) * 4;
    if (i + 3 < n) {
        float4 v = *(const float4*)(in + i);
        u16 o[4] = { f2bf(v.x), f2bf(v.y), f2bf(v.z), f2bf(v.w) };
        *(uint2*)(out + i) = *(const uint2*)o;
    }
}

// three QKV weight matrices -> concat bf16 buffer, one launch (grid.y = seg)
__global__ void cvt_w3(const float* __restrict__ Wq, const float* __restrict__ Wk,
                       const float* __restrict__ Wv, u16* __restrict__ out)
{
    const int seg = blockIdx.y;
    const float* src = (seg == 0) ? Wq : (seg == 1) ? Wk : Wv;
    int i = (blockIdx.x * 256 + threadIdx.x) * 4;
    float4 v = *(const float4*)(src + i);
    u16 o[4] = { f2bf(v.x), f2bf(v.y), f2bf(v.z), f2bf(v.w) };
    *(uint2*)(out + (size_t)seg * E_DIM * E_DIM + i) = *(const uint2*)o;
}

// ---------------------------------------------------------------------------
// ctx = a + b  (bf16 in, fp32 add, bf16 out)
// ---------------------------------------------------------------------------
__global__ void combine_ctx(const u16* __restrict__ a, const u16* __restrict__ b,
                            u16* __restrict__ c, int n)
{
    int i = (blockIdx.x * 256 + threadIdx.x) * 4;
    if (i + 3 < n) {
        uint2 ua = *(const uint2*)(a + i);
        uint2 ub = *(const uint2*)(b + i);
        const u16* pa = (const u16*)&ua; const u16* pb = (const u16*)&ub;
        u16 o[4];
#pragma unroll
        for (int j = 0; j < 4; ++j) o[j] = f2bf(bf2f(pa[j]) + bf2f(pb[j]));
        *(uint2*)(c + i) = *(const uint2*)o;
    }
}

// ---------------------------------------------------------------------------
// Fused QKV projection GEMM — BK=64 (R14): halves barrier/drain count per
// block (16 iters, 32 MFMA each).  LDS staging is XOR-SWIZZLED via the
// global SOURCE address (m173 pattern: global_load_lds dest must stay
// linear): lane (row lrow, slot lg) loads granule lg^lrow of its row, so
// the reader's b128 at logical granule g for row rr lives at physical
// granule g^(rr&7) -> read banks spread 2 lanes/bank (free); without it
// BK=64's 128B row pitch is a 16-way conflict.
// ---------------------------------------------------------------------------
__global__ __launch_bounds__(256)
void gemm_qkv(const u16* __restrict__ A, const u16* __restrict__ W3,
              const float* __restrict__ bq, const float* __restrict__ bk,
              const float* __restrict__ bv,
              u16* __restrict__ Qb, u16* __restrict__ Kb, u16* __restrict__ Vtb)
{
    __shared__ u16 Al[128 * 64];
    __shared__ u16 Bl[128 * 64];
    const int K = E_DIM;
    const int t = threadIdx.x;
    const int w = t >> 6, lane = t & 63;
    const int quad = lane >> 4, lm = lane & 15;
    const int wy = w >> 1, wx = w & 1;
    const int m0 = blockIdx.x * 128, n0 = blockIdx.y * 128;
    const int lrow   = lane >> 3;             // 0..7 within 8-row group
    const int lcolsw = ((lane & 7) ^ lrow) * 8;   // swizzled source col (u16)

    f32x4 acc[4][4] = {};

    for (int kb = 0; kb < K; kb += 64) {
        __syncthreads();
#pragma unroll
        for (int i = 0; i < 4; ++i) {
            const int r0 = w * 32 + i * 8;
            load_lds16(A  + (size_t)(m0 + r0 + lrow) * K + kb + lcolsw, &Al[r0 * 64]);
            load_lds16(W3 + (size_t)(n0 + r0 + lrow) * K + kb + lcolsw, &Bl[r0 * 64]);
        }
        __syncthreads();

#pragma unroll
        for (int kk = 0; kk < 2; ++kk) {
            bf16x8 af[4], bfr[4];
#pragma unroll
            for (int i = 0; i < 4; ++i) {
                const int rr = wy * 64 + i * 16 + lm;
                const int pg = (kk * 4 + quad) ^ (rr & 7);
                af[i] = *(const bf16x8*)(Al + rr * 64 + pg * 8);
            }
#pragma unroll
            for (int j = 0; j < 4; ++j) {
                const int rr = wx * 64 + j * 16 + lm;
                const int pg = (kk * 4 + quad) ^ (rr & 7);
                bfr[j] = *(const bf16x8*)(Bl + rr * 64 + pg * 8);
            }
#pragma unroll
            for (int i = 0; i < 4; ++i)
#pragma unroll
                for (int j = 0; j < 4; ++j)
                    acc[i][j] = __builtin_amdgcn_mfma_f32_16x16x32_bf16(af[i], bfr[j], acc[i][j], 0, 0, 0);
        }
    }

    const int seg = n0 >> 10;            // 0=Q, 1=K, 2=V
    const int nl0 = n0 & 1023;
    const float* bs = (seg == 0) ? bq : (seg == 1) ? bk : bv;

    if (seg < 2) {
        u16* dst = (seg == 0) ? Qb : Kb;
        const float scl = (seg == 0) ? QSCALE : 1.0f;
#pragma unroll
        for (int j = 0; j < 4; ++j) {
            const int n = nl0 + wx * 64 + j * 16 + lm;
            const float bias = bs[n];
#pragma unroll
            for (int i = 0; i < 4; ++i) {
                const int mrow = m0 + wy * 64 + i * 16 + quad * 4;
#pragma unroll
                for (int rg = 0; rg < 4; ++rg)
                    dst[(size_t)(mrow + rg) * E_DIM + n] = f2bf((acc[i][j][rg] + bias) * scl);
            }
        }
    } else {
        // V: fp16, transposed -> Vt[b][e][s]
#pragma unroll
        for (int j = 0; j < 4; ++j) {
            const int n = nl0 + wx * 64 + j * 16 + lm;
            const float bias = bs[n];
#pragma unroll
            for (int i = 0; i < 4; ++i) {
                const int mrow = m0 + wy * 64 + i * 16 + quad * 4;
                const int batch = mrow >> 11;
                const int sloc  = mrow & 2047;
                u16 o[4];
#pragma unroll
                for (int rg = 0; rg < 4; ++rg) {
                    union { _Float16 h; u16 u; } cv;
                    cv.h = (_Float16)(acc[i][j][rg] + bias);
                    o[rg] = cv.u;
                }
                *(uint2*)&Vtb[(size_t)batch * E_DIM * S_LEN + (size_t)n * S_LEN + sloc]
                    = *(const uint2*)o;
            }
        }
    }
}

// ---------------------------------------------------------------------------
// Output projection GEMM — same BK=64 + source-swizzle change.
// ---------------------------------------------------------------------------
__global__ __launch_bounds__(256)
void gemm_wo(const u16* __restrict__ A, const u16* __restrict__ B,
             const float* __restrict__ bias, float* __restrict__ C)
{
    __shared__ u16 Al[128 * 64];
    __shared__ u16 Bl[128 * 64];
    const int K = E_DIM, N = E_DIM;
    const int t = threadIdx.x;
    const int w = t >> 6, lane = t & 63;
    const int quad = lane >> 4, lm = lane & 15;
    const int wy = w >> 1, wx = w & 1;
    const int m0 = blockIdx.x * 128, n0 = blockIdx.y * 128;
    const int lrow   = lane >> 3;
    const int lcolsw = ((lane & 7) ^ lrow) * 8;

    f32x4 acc[4][4] = {};

    for (int kb = 0; kb < K; kb += 64) {
        __syncthreads();
#pragma unroll
        for (int i = 0; i < 4; ++i) {
            const int r0 = w * 32 + i * 8;
            load_lds16(A + (size_t)(m0 + r0 + lrow) * K + kb + lcolsw, &Al[r0 * 64]);
            load_lds16(B + (size_t)(n0 + r0 + lrow) * K + kb + lcolsw, &Bl[r0 * 64]);
        }
        __syncthreads();

#pragma unroll
        for (int kk = 0; kk < 2; ++kk) {
            bf16x8 af[4], bfr[4];
#pragma unroll
            for (int i = 0; i < 4; ++i) {
                const int rr = wy * 64 + i * 16 + lm;
                const int pg = (kk * 4 + quad) ^ (rr & 7);
                af[i] = *(const bf16x8*)(Al + rr * 64 + pg * 8);
            }
#pragma unroll
            for (int j = 0; j < 4; ++j) {
                const int rr = wx * 64 + j * 16 + lm;
                const int pg = (kk * 4 + quad) ^ (rr & 7);
                bfr[j] = *(const bf16x8*)(Bl + rr * 64 + pg * 8);
            }
#pragma unroll
            for (int i = 0; i < 4; ++i)
#pragma unroll
                for (int j = 0; j < 4; ++j)
                    acc[i][j] = __builtin_amdgcn_mfma_f32_16x16x32_bf16(af[i], bfr[j], acc[i][j], 0, 0, 0);
        }
    }

#pragma unroll
    for (int j = 0; j < 4; ++j) {
        const int n = n0 + wx * 64 + j * 16 + lm;
        const float bs = bias[n];
#pragma unroll
        for (int i = 0; i < 4; ++i) {
            const int mrow = m0 + wy * 64 + i * 16 + quad * 4;
#pragma unroll
            for (int rg = 0; rg < 4; ++rg)
                C[(size_t)(mrow + rg) * N + n] = acc[i][j][rg] + bs;
        }
    }
}

// ---------------------------------------------------------------------------
// attn_v17 = v16 3-stage pipeline + K REGISTER PREFETCH (chunk c+1's K
// loaded into regs during phase c, consumed next phase — removes the
// phase-start K-load -> MFMA dependency).  Steady loop 2x-unrolled with
// NAMED kA/kB arrays inside macros (no fn params / runtime indexing —
// R4's spill trap avoided by construction).  +32 arch regs: 148+64acc
// = 212 <= 256 quantum, occupancy unchanged.
// ---------------------------------------------------------------------------
#define KLOAD(KX, KOFF)                                                       \
  _Pragma("unroll")                                                           \
  for (int kt = 0; kt < 2; ++kt)                                              \
    _Pragma("unroll")                                                         \
    for (int hp = 0; hp < 2; ++hp) {                                          \
      KX[kt][hp][0] = *(const bf16x8*)(K + kmat                               \
                      + (size_t)((KOFF) + kt * 16 + lm) * E_DIM               \
                      + (h0 + hp) * 64 + quad * 8);                           \
      KX[kt][hp][1] = *(const bf16x8*)(K + kmat                               \
                      + (size_t)((KOFF) + kt * 16 + lm) * E_DIM               \
                      + (h0 + hp) * 64 + 32 + quad * 8);                      \
    }

#define QKT_R(KX, S4W)                                                        \
  _Pragma("unroll")                                                           \
  for (int kt = 0; kt < 2; ++kt) {                                            \
    f32x4 sacc_[2][2];                                                        \
    _Pragma("unroll")                                                         \
    for (int hp = 0; hp < 2; ++hp)                                            \
      _Pragma("unroll")                                                       \
      for (int s = 0; s < 2; ++s) {                                           \
        f32x4 sf_ = {};                                                       \
        sf_ = __builtin_amdgcn_mfma_f32_16x16x32_bf16(KX[kt][hp][0], qf[s][hp][0], sf_, 0, 0, 0); \
        sf_ = __builtin_amdgcn_mfma_f32_16x16x32_bf16(KX[kt][hp][1], qf[s][hp][1], sf_, 0, 0, 0); \
        sacc_[hp][s] = sf_;                                                   \
      }                                                                       \
    _Pragma("unroll")                                                         \
    for (int s = 0; s < 2; ++s)                                               \
      _Pragma("unroll")                                                       \
      for (int rg = 0; rg < 4; ++rg) {                                        \
        union { h16x2 v; unsigned u; } pk_;                                   \
        pk_.v = __builtin_amdgcn_cvt_pkrtz(sacc_[0][s][rg], sacc_[1][s][rg]); \
        const int kl_  = kt * 16 + quad * 4 + rg;                             \
        const int qph_ = ((s * 16 + lm) + 8 * quad) & 31;                     \
        *(unsigned*)((S4W) + (size_t)(kl_ * 32 + qph_) * 18 + 2 * w) = pk_.u; \
      }                                                                       \
  }

#define SM_ST(S4R, P5W)                                                       \
  {                                                                           \
    float pv0[16], pv1[16];                                                   \
    _Pragma("unroll")                                                         \
    for (int e = 0; e < 2; ++e) {                                             \
      const int kk_ = 2 * sj + e;                                             \
      const u16* base_ = (S4R) + (size_t)(kk_ * 32 + qrot) * 18;              \
      union { uint4 u; __fp16 hh[8]; } r0_, r1_;                              \
      r0_.u = *(const uint4*)(base_);                                         \
      r1_.u = *(const uint4*)(base_ + 8);                                     \
      float s_[16];                                                           \
      _Pragma("unroll")                                                       \
      for (int z = 0; z < 8; ++z) {                                           \
        s_[z] = (float)r0_.hh[z]; s_[8 + z] = (float)r1_.hh[z];               \
      }                                                                       \
      const float m_ =                                                        \
          fmaxf(fmaxf(fmaxf(fmaxf(s_[0], s_[1]), fmaxf(s_[2], s_[3])),        \
                      fmaxf(fmaxf(s_[4], s_[5]), fmaxf(s_[6], s_[7]))),       \
                fmaxf(fmaxf(fmaxf(s_[8], s_[9]), fmaxf(s_[10], s_[11])),      \
                      fmaxf(fmaxf(s_[12], s_[13]), fmaxf(s_[14], s_[15])))); \
      _Pragma("unroll")                                                       \
      for (int hh = 0; hh < 16; ++hh)                                         \
        s_[hh] = __builtin_amdgcn_exp2f(s_[hh] - m_);                         \
      const float sum_ =                                                      \
          (((s_[0] + s_[1]) + (s_[2] + s_[3])) + ((s_[4] + s_[5]) + (s_[6] + s_[7]))) + \
          (((s_[8] + s_[9]) + (s_[10] + s_[11])) + ((s_[12] + s_[13]) + (s_[14] + s_[15]))); \
      const float inv_ = __builtin_amdgcn_rcpf(sum_);                         \
      if (e == 0) {                                                           \
        _Pragma("unroll")                                                     \
        for (int hh = 0; hh < 16; ++hh) pv0[hh] = s_[hh] * inv_;              \
      } else {                                                                \
        _Pragma("unroll")                                                     \
        for (int hh = 0; hh < 16; ++hh) pv1[hh] = s_[hh] * inv_;              \
      }                                                                       \
    }                                                                         \
    _Pragma("unroll")                                                         \
    for (int hh = 0; hh < 16; ++hh) {                                         \
      union { h16x2 v; unsigned u; } cv_;                                     \
      cv_.v = __builtin_amdgcn_cvt_pkrtz(pv0[hh], pv1[hh]);                   \
      *(unsigned*)((P5W) + (size_t)hh * 1280 + sq * 40 + 2 * sj) = cv_.u;     \
    }                                                                         \
  }

#define V_ST(KOFF)                                                            \
  _Pragma("unroll")                                                           \
  for (int hp = 0; hp < 2; ++hp)                                              \
    _Pragma("unroll")                                                         \
    for (int dt = 0; dt < 4; ++dt)                                            \
      vf[hp][dt] = *(const f16x8*)(Vt + vtb                                   \
                   + (size_t)((h0 + hp) * 64 + dt * 16 + lm) * S_LEN          \
                   + (KOFF) + quad * 8);

#define PV_ST(P5R)                                                            \
  _Pragma("unroll")                                                           \
  for (int hp = 0; hp < 2; ++hp)                                              \
    _Pragma("unroll")                                                         \
    for (int s = 0; s < 2; ++s) {                                             \
      f16x8 pa_ = *(const f16x8*)((P5R) + (size_t)(h0 + hp) * 1280            \
                                  + (s * 16 + lm) * 40 + quad * 8);           \
      _Pragma("unroll")                                                       \
      for (int dt = 0; dt < 4; ++dt)                                          \
        oacc[hp][s][dt] = __builtin_amdgcn_mfma_f32_16x16x32_f16(             \
                              pa_, vf[hp][dt], oacc[hp][s][dt], 0, 0, 0);     \
    }

#define PHASE_END                                                             \
  asm volatile("s_waitcnt lgkmcnt(0)" ::: "memory");                          \
  __builtin_amdgcn_s_barrier();

__global__ __launch_bounds__(512, 2)
void attn_v17(const u16* __restrict__ Q, const u16* __restrict__ K,
              const u16* __restrict__ Vt, u16* __restrict__ ctxA,
              u16* __restrict__ ctxB)
{
    // S4h[2] @ 0 / 18432 u16; P5[2] @ 36864 / 57344 u16.  152 KB total.
    __shared__ __align__(16) u16 smem[77824];

    const int t     = threadIdx.x;   // 0..511
    const int w     = t >> 6;        // 0..7
    const int lane  = t & 63;
    const int quad  = lane >> 4, lm = lane & 15;

    // combo -> XCD-pair pinning (model: XCD = blockIdx % 8).
    const int i     = blockIdx.x;        // 0..255
    const int xcd   = i & 7;
    const int combo = xcd >> 1;          // 0..3
    const int b     = combo >> 1;
    const int khalf = combo & 1;
    const int slot  = i >> 3;            // 0..31
    const int qt    = ((xcd & 1) << 5) | slot;   // 0..63
    const int q0    = qt * 32;

    const size_t qbase = ((size_t)b * S_LEN + q0) * E_DIM;
    const size_t kmat  = (size_t)b * S_LEN * E_DIM;
    const size_t vtb   = (size_t)b * E_DIM * S_LEN;

    const int h0 = 2 * w;                // this wave's first head

    // Q fragments: [subtile][head-pair][hf], loop-invariant (32 regs)
    bf16x8 qf[2][2][2];
#pragma unroll
    for (int s = 0; s < 2; ++s)
#pragma unroll
        for (int hp = 0; hp < 2; ++hp)
#pragma unroll
            for (int hf = 0; hf < 2; ++hf)
                qf[s][hp][hf] = *(const bf16x8*)(Q + qbase
                                + (size_t)(s * 16 + lm) * E_DIM
                                + (h0 + hp) * 64 + hf * 32 + quad * 8);

    f32x4 oacc[2][2][4] = {};   // [hp][subtile][dtile] = 64 acc regs
    f16x8 vf[2][4];             // V regs, re-filled each phase
    bf16x8 kA[2][2][2], kB[2][2][2];   // K ping-pong prefetch (32 regs)
    const int kbeg = khalf * (S_LEN / 2);
    const int sq = t & 31, sj = t >> 5;  // softmax: q=sq, k in {2sj, 2sj+1}
    const int qrot = (sq + 8 * ((sj >> 1) & 3)) & 31;

    u16* const S4_0 = smem;
    u16* const S4_1 = smem + 18432;
    u16* const P5_0 = smem + 36864;
    u16* const P5_1 = smem + 57344;

    // ---- pipeline prologue ----
    KLOAD(kA, kbeg)                          // K(0)
    QKT_R (kA, S4_0)                         // chunk 0 -> S4h[0]
    KLOAD (kB, kbeg + 32)                    // K(1) prefetch
    PHASE_END
    QKT_R (kB, S4_1)                         // chunk 1 -> S4h[1]
    KLOAD (kA, kbeg + 64)                    // K(2) prefetch
    SM_ST (S4_0, P5_0)                       // softmax 0 -> P5[0]
    PHASE_END

    // ---- steady state, 2x unrolled: c=2+2i (kA) then c=3+2i (kB) ----
    for (int it = 0; it < 15; ++it) {
        const int c0 = 2 + 2 * it;           // even chunk
        // even phase: QK^T(c0) from kA | prefetch K(c0+1) -> kB
        V_ST  (kbeg + (c0 - 2) * 32)
        QKT_R (kA, S4_0)
        KLOAD (kB, kbeg + (c0 + 1) * 32)
        SM_ST (S4_1, P5_1)                   // SM(c0-1, odd)
        PV_ST (P5_0)                         // PV(c0-2, even)
        PHASE_END
        // odd phase: QK^T(c0+1) from kB | prefetch K(c0+2) -> kA
        const int nk = (c0 + 2 < 32) ? (c0 + 2) : 31;   // clamp last prefetch
        V_ST  (kbeg + (c0 - 1) * 32)
        QKT_R (kB, S4_1)
        KLOAD (kA, kbeg + nk * 32)
        SM_ST (S4_0, P5_0)                   // SM(c0, even)
        PV_ST (P5_1)                         // PV(c0-1, odd)
        PHASE_END
    }

    // ---- pipeline drain: SM(31)|PV(30), then PV(31) ----
    V_ST  (kbeg + 30 * 32)
    SM_ST (S4_1, P5_1)                       // chunk 31
    PV_ST (P5_0)                             // chunk 30
    PHASE_END
    V_ST  (kbeg + 31 * 32)
    PV_ST (P5_1)                             // chunk 31

    __syncthreads();
    u16* Ol = smem;          // [32 q][1024 e] = 32768 u16 <= 77824 u16
#pragma unroll
    for (int hp = 0; hp < 2; ++hp) {
        const int h = h0 + hp;
#pragma unroll
        for (int s = 0; s < 2; ++s)
#pragma unroll
            for (int dt = 0; dt < 4; ++dt)
#pragma unroll
                for (int rg = 0; rg < 4; ++rg)
                    Ol[(size_t)(s * 16 + quad * 4 + rg) * 1024 + h * 64 + dt * 16 + lm]
                        = f2bf(oacc[hp][s][dt][rg]);
    }
    __syncthreads();
    u16* dst = khalf ? ctxB : ctxA;
#pragma unroll
    for (int i2 = 0; i2 < 8; ++i2) {
        const int unit = i2 * 512 + t;
        const int r = unit >> 7, cu = unit & 127;   // r 0..31
        *(bf16x8*)(dst + ((size_t)b * S_LEN + q0 + r) * E_DIM + cu * 8) =
            *(const bf16x8*)(Ol + (size_t)r * 1024 + cu * 8);
    }
}

#undef KLOAD
#undef QKT_R
#undef SM_ST
#undef V_ST
#undef PV_ST
#undef PHASE_END

// ---------------------------------------------------------------------------
extern "C" void kernel_launch(void* const* d_in, const int* in_sizes, int n_in,
                              void* d_out, int out_size, void* d_ws, size_t ws_size,
                              hipStream_t stream)
{
    const float* x  = (const float*)d_in[0];
    const float* Wq = (const float*)d_in[1];
    const float* bq = (const float*)d_in[2];
    const float* Wk = (const float*)d_in[3];
    const float* bk = (const float*)d_in[4];
    const float* Wv = (const float*)d_in[5];
    const float* bv = (const float*)d_in[6];
    const float* Wo = (const float*)d_in[7];
    const float* bo = (const float*)d_in[8];
    float* out = (float*)d_out;

    // bf16/fp16 workspace (u16 elems), 56 MB:
    const size_t MAT = (size_t)M_ROWS * E_DIM;   // 4M elems
    const size_t WSZ = (size_t)E_DIM * E_DIM;    // 1M elems
    u16* xb   = (u16*)d_ws;          // x; later combined ctx
    u16* W3   = xb   + MAT;          // Wq|Wk|Wv concat [3072][1024]
    u16* Wob  = W3   + 3 * WSZ;
    u16* Qb   = Wob  + WSZ;
    u16* Kb   = Qb   + MAT;
    u16* Vtb  = Kb   + MAT;          // V transposed [b][e][s], FP16
    u16* ctxA = Vtb  + MAT;
    u16* ctxB = ctxA + MAT;

    // 1) convert inputs to bf16 (QKV weights in one merged launch)
    cvt_bf16<<<(int)(MAT / 1024), 256, 0, stream>>>(x, xb, (int)MAT);
    dim3 wgrid(WSZ / 1024, 3);
    cvt_w3<<<wgrid, 256, 0, stream>>>(Wq, Wk, Wv, W3);
    cvt_bf16<<<(int)(WSZ / 1024), 256, 0, stream>>>(Wo, Wob, (int)WSZ);

    // 2) fused QKV projection (BK=64, source-swizzled staging)
    dim3 qkvgrid(M_ROWS / 128, 3 * E_DIM / 128);   // 32 x 24 = 768 blocks
    gemm_qkv<<<qkvgrid, 256, 0, stream>>>(xb, W3, bq, bk, bv, Qb, Kb, Vtb);

    // 3) fused MFMA attention: 3-stage pipelined + K reg-prefetch
    attn_v17<<<BATCH * 64 * 2, 512, 0, stream>>>(Qb, Kb, Vtb, ctxA, ctxB);

    // 4) combine k-halves into xb (x is dead)
    combine_ctx<<<(int)(MAT / 1024), 256, 0, stream>>>(ctxA, ctxB, xb, (int)MAT);

    // 5) output projection (BK=64, source-swizzled staging; fp32 out)
    dim3 ogrid(M_ROWS / 128, E_DIM / 128);         // 32 x 8
    gemm_wo<<<ogrid, 256, 0, stream>>>(xb, Wob, bo, out);
}